// Round 1
// baseline (489.738 us; speedup 1.0000x reference)
//
#include <hip/hip_runtime.h>
#include <stdint.h>

#define MDIM 8192
#define NDIM 4096
#define KDIM 4096
#define FINAL_SZ (NDIM * KDIM / 4)   // 4,194,304 packed bytes
#define BM 128
#define BN 128
#define BK 64

typedef __attribute__((ext_vector_type(8))) short short8;
typedef __attribute__((ext_vector_type(4))) float floatx4;

typedef const __attribute__((address_space(1))) void global_cv;
typedef __attribute__((address_space(3))) void lds_v;

__device__ __forceinline__ unsigned short f2bf_rne(float f) {
    union { float f; uint32_t u; } a; a.f = f;
    uint32_t u = a.u;
    u += 0x7FFFu + ((u >> 16) & 1u);           // round-to-nearest-even (inputs are finite normals)
    return (unsigned short)(u >> 16);
}

// ---------- kernel 1: x fp32 -> bf16 ----------
__global__ void cvt_x_kernel(const float* __restrict__ x, unsigned short* __restrict__ xb) {
    int i = blockIdx.x * blockDim.x + threadIdx.x;   // one float4 per thread, exact cover
    float4 v = ((const float4*)x)[i];
    ushort4 o;
    o.x = f2bf_rne(v.x); o.y = f2bf_rne(v.y);
    o.z = f2bf_rne(v.z); o.w = f2bf_rne(v.w);
    ((ushort4*)xb)[i] = o;
}

// ---------- detect: is pw a packed uint8 buffer or int32-widened? ----------
__global__ void detect_kernel(const unsigned int* __restrict__ pw, int* __restrict__ flag) {
    unsigned int v = pw[threadIdx.x];                // 64 words
    unsigned long long m = __ballot(v > 255u);       // any word >255 => raw packed uint8 bytes
    if (threadIdx.x == 0) *flag = (m != 0ull) ? 1 : 0;
}

// code 0,1,2,3 -> bf16 of -1,0,1,2
__device__ __forceinline__ unsigned short code2bf(unsigned int c) {
    return (unsigned short)((0x40003F800000BF80ull >> (c * 16)) & 0xFFFFull);
}

// ---------- kernel 2: unpack ternary -> bf16 W[4096][4096] ----------
__global__ void unpack_w_kernel(const void* __restrict__ pwv, const int* __restrict__ flag,
                                unsigned short* __restrict__ w) {
    int t = blockIdx.x * blockDim.x + threadIdx.x;   // 4 packed bytes per thread
    unsigned int b4;
    if (*flag) {
        b4 = ((const unsigned int*)pwv)[t];
    } else {
        int4 q = ((const int4*)pwv)[t];              // each int holds one byte value
        b4 = (unsigned)(q.x & 255) | ((unsigned)(q.y & 255) << 8)
           | ((unsigned)(q.z & 255) << 16) | ((unsigned)(q.w & 255) << 24);
    }
    int j  = t << 2;
    int r  = j >> 12;        // packed row 0..1023
    int ci = j & 4095;       // column
#pragma unroll
    for (int p = 0; p < 4; ++p) {
        ushort4 o;
        o.x = code2bf((b4 >> (2 * p)) & 3u);
        o.y = code2bf((b4 >> (8 + 2 * p)) & 3u);
        o.z = code2bf((b4 >> (16 + 2 * p)) & 3u);
        o.w = code2bf((b4 >> (24 + 2 * p)) & 3u);
        *(ushort4*)(w + (((size_t)((p << 10) + r)) << 12) + ci) = o;  // w[p*1024+r][ci..ci+3]
    }
}

// ---------- kernel 3: C = clip((A . B^T) * scale + bias) ----------
// A: x_bf16 [M][K] row-major, B: w_bf16 [N][K] row-major, C: fp32 [M][N]
// 128x128 block tile, BK=64, 4 waves (2x2 of 64x64), 16x16x32 bf16 MFMA.
// LDS tiles stored row-major (row stride 128 B) with XOR chunk swizzle:
// 16B chunk c of row r lives at physical slot c ^ (r & 7). Swizzle is applied
// on the GLOBAL address during global_load_lds (LDS side must stay lane-contiguous).
__global__ __launch_bounds__(256) void gemm_ternary(
    const unsigned short* __restrict__ A,
    const unsigned short* __restrict__ B,
    const float* __restrict__ scale,
    const float* __restrict__ bias,
    float* __restrict__ C) {
    __shared__ __align__(16) unsigned short lA[BM * BK];  // 16 KiB
    __shared__ __align__(16) unsigned short lB[BN * BK];  // 16 KiB

    const int tid  = threadIdx.x;
    const int lane = tid & 63;
    const int wave = tid >> 6;
    const int m0 = blockIdx.y * BM;
    const int n0 = blockIdx.x * BN;
    const int wm = (wave >> 1) * 64;   // wave's 64x64 subtile
    const int wn = (wave & 1) * 64;

    // --- staging setup: each wave issues 4 A + 4 B global_load_lds (1024 B each) per K-step
    const char* gA[4];
    const char* gB[4];
    unsigned short* lAd[4];
    unsigned short* lBd[4];
#pragma unroll
    for (int t = 0; t < 4; ++t) {
        int row  = wave * 32 + t * 8 + (lane >> 3);       // tile row this lane sources
        int clog = (lane & 7) ^ (row & 7);                // swizzled global 16B chunk
        gA[t] = (const char*)(A + (size_t)(m0 + row) * KDIM) + clog * 16;
        gB[t] = (const char*)(B + (size_t)(n0 + row) * KDIM) + clog * 16;
        lAd[t] = lA + (wave * 32 + t * 8) * 64;           // wave-uniform LDS base
        lBd[t] = lB + (wave * 32 + t * 8) * 64;
    }

    floatx4 acc[4][4];
#pragma unroll
    for (int i = 0; i < 4; ++i)
#pragma unroll
        for (int j = 0; j < 4; ++j)
            acc[i][j] = (floatx4){0.f, 0.f, 0.f, 0.f};

    for (int k0 = 0; k0 < KDIM; k0 += BK) {
#pragma unroll
        for (int t = 0; t < 4; ++t) {
            __builtin_amdgcn_global_load_lds((global_cv*)gA[t], (lds_v*)lAd[t], 16, 0, 0);
            __builtin_amdgcn_global_load_lds((global_cv*)gB[t], (lds_v*)lBd[t], 16, 0, 0);
            gA[t] += BK * 2;
            gB[t] += BK * 2;
        }
        __syncthreads();   // compiler emits s_waitcnt vmcnt(0) before s_barrier

#pragma unroll
        for (int kt = 0; kt < 2; ++kt) {
            short8 af[4], bfr[4];
#pragma unroll
            for (int i = 0; i < 4; ++i) {
                // A-frag: lane holds A[m = lane&15][k = (lane>>4)*8 + j]
                int rowA = wm + i * 16 + (lane & 15);
                int cA   = (kt * 4 + (lane >> 4)) ^ (rowA & 7);
                af[i] = *(const short8*)(lA + rowA * 64 + cA * 8);
                int rowB = wn + i * 16 + (lane & 15);
                int cB   = (kt * 4 + (lane >> 4)) ^ (rowB & 7);
                bfr[i] = *(const short8*)(lB + rowB * 64 + cB * 8);
            }
#pragma unroll
            for (int mi = 0; mi < 4; ++mi)
#pragma unroll
                for (int ni = 0; ni < 4; ++ni)
                    acc[mi][ni] = __builtin_amdgcn_mfma_f32_16x16x32_bf16(
                        af[mi], bfr[ni], acc[mi][ni], 0, 0, 0);
        }
        __syncthreads();
    }

    // --- epilogue: C/D layout col = lane&15 (n), row = (lane>>4)*4 + reg (m)
    float sc[4], bi[4];
#pragma unroll
    for (int ni = 0; ni < 4; ++ni) {
        int n  = n0 + wn + ni * 16 + (lane & 15);
        sc[ni] = scale[n];
        bi[ni] = bias[n];
    }
#pragma unroll
    for (int mi = 0; mi < 4; ++mi) {
#pragma unroll
        for (int r = 0; r < 4; ++r) {
            int m = m0 + wm + mi * 16 + (lane >> 4) * 4 + r;
            float* Crow = C + (size_t)m * NDIM;
#pragma unroll
            for (int ni = 0; ni < 4; ++ni) {
                int n = n0 + wn + ni * 16 + (lane & 15);
                float v = acc[mi][ni][r] * sc[ni] + bi[ni];
                v = fminf(100.f, fmaxf(-100.f, v));
                Crow[n] = v;
            }
        }
    }
}

extern "C" void kernel_launch(void* const* d_in, const int* in_sizes, int n_in,
                              void* d_out, int out_size, void* d_ws, size_t ws_size,
                              hipStream_t stream) {
    const float* x  = (const float*)d_in[0];
    const void*  pw = d_in[1];                     // packed uint8 OR int32-widened; detected on device
    const float* scale = (const float*)d_in[2];
    const float* bias  = (const float*)d_in[3];
    float* out = (float*)d_out;

    // workspace layout: [0,64MiB) x_bf16 | [64,96MiB) w_bf16 | flag
    unsigned short* xb = (unsigned short*)d_ws;
    unsigned short* wb = xb + (size_t)MDIM * KDIM;
    int* flag = (int*)((char*)d_ws + (size_t)(MDIM * 2 + NDIM * 2) * KDIM / 2 * 0 +
                       (size_t)MDIM * KDIM * 2 + (size_t)NDIM * KDIM * 2);

    detect_kernel<<<1, 64, 0, stream>>>((const unsigned int*)pw, flag);
    cvt_x_kernel<<<(MDIM * KDIM / 4) / 256, 256, 0, stream>>>(x, xb);
    unpack_w_kernel<<<(FINAL_SZ / 4) / 256, 256, 0, stream>>>(pw, flag, wb);

    dim3 grid(NDIM / BN, MDIM / BM);   // 32 x 64
    gemm_ternary<<<grid, 256, 0, stream>>>(xb, wb, scale, bias, out);
}